// Round 18
// baseline (1423.397 us; speedup 1.0000x reference)
//
#include <hip/hip_runtime.h>
#include <hip/hip_bf16.h>

typedef __hip_bfloat16 bf16;
typedef unsigned short u16;
typedef unsigned long long u64;
using frag  = __attribute__((ext_vector_type(8))) short;   // 8 bf16
using f32x4 = __attribute__((ext_vector_type(4))) float;   // 4 fp32 acc

static constexpr int T_  = 128;
static constexpr int B_  = 512;
static constexpr int H_  = 512;
static constexpr int K_  = 512;
static constexpr int G4_ = 2048;
static constexpr int NWG = 256;

// dynamic LDS: frag-blocked weights 128KB + exchange tiles 32KB = 160 KiB exactly
static constexpr size_t W_BYTES = 131072;
static constexpr size_t X_BYTES = 32768;
static constexpr size_t SMEM_BYTES = W_BYTES + X_BYTES;   // 163840

// ---------------- setup kernels ----------------

__global__ void k_f32_to_bf16_v4(const float4* __restrict__ src,
                                 ushort4* __restrict__ dst, int n4) {
  int i = blockIdx.x * blockDim.x + threadIdx.x;
  int stride = gridDim.x * blockDim.x;
  for (; i < n4; i += stride) {
    float4 v = src[i];
    ushort4 o;
    bf16 t0 = __float2bfloat16(v.x); o.x = *reinterpret_cast<u16*>(&t0);
    bf16 t1 = __float2bfloat16(v.y); o.y = *reinterpret_cast<u16*>(&t1);
    bf16 t2 = __float2bfloat16(v.z); o.z = *reinterpret_cast<u16*>(&t2);
    bf16 t3 = __float2bfloat16(v.w); o.w = *reinterpret_cast<u16*>(&t3);
    dst[i] = o;
  }
}

__global__ void k_bias(const float* __restrict__ bih0, const float* __restrict__ bhh0,
                       const float* __restrict__ bih1, const float* __restrict__ bhh1,
                       float* __restrict__ bsum0, float* __restrict__ bsum1) {
  int i = blockIdx.x * blockDim.x + threadIdx.x;
  if (i < G4_) {
    bsum0[i] = bih0[i] + bhh0[i];
    bsum1[i] = bih1[i] + bhh1[i];
  }
}

// initial h into per-layer L2-local buffers: layer0 -> bufA0 par0, layer1 -> bufA1 par1
__global__ void k_init2(const float* __restrict__ h0,
                        u16* __restrict__ bufA0, u16* __restrict__ bufA1) {
  int i = blockIdx.x * blockDim.x + threadIdx.x;
  int n = B_ * H_;
  if (i < n) {
    bf16 a = __float2bfloat16(h0[i]);
    bf16 b = __float2bfloat16(h0[n + i]);
    bufA0[i] = *reinterpret_cast<u16*>(&a);          // parity 0
    bufA1[n + i] = *reinterpret_cast<u16*>(&b);      // parity 1
  }
}

__global__ void k_zero(int* p) {
  int i = blockIdx.x * blockDim.x + threadIdx.x;
  if (i < 256) p[i] = 0;
}

// ---------------- persistent LSTM kernel ----------------
// R17 base + 16-wave TLP. 256 WGs x 1024 thr (16 waves -> 4 waves/SIMD).
// Mapping: lb = wg&7 -> layer = lb>>2, bg = lb&3 ; cg = wg>>3.
// WG owns rows [bg*128,+128) x h-cols [cg*16,+16).
// Waves: rt = wave&7 (16-row tile, rows [rt*16,+16)), hf = wave>>3:
//   hf=0: x-part (K 0..511 @ W_ih) -> after exchange, final gates + elementwise
//   hf=1: h-part (K 0..511 @ W_hh, reset-masked) -> writes partials to LDS
// (&7 / >>3 interleaves hf across SIMDs: each SIMD gets 2 hf0 + 2 hf1 waves.)
// Per wave: 16 A-loads + 64 B-ds_reads + 64 MFMA (half of R17's chain length).
// Exchange: hf1 writes acc[ni] as f32x4 at ((rt*4+ni)*64+lane)*16B -> 32KB,
// lane-consecutive (conflict-free); 1 sync; hf0 adds. hstage reuses the own-rt
// tile region (in-wave DS ordering, no extra sync).
// Data paths (= R17): frag-blocked weights; h-self bufA plain L2 + per-phase
// buffer_inv sc0; cross-layer h0 via t-indexed h0seq (L0 agent-atomic stores,
// L1 plain cached loads); asymmetric flag barrier (L0 own set, L1 pair set).
__global__ __launch_bounds__(1024, 4)
void k_main(const u16* __restrict__ latb,
            const u16* __restrict__ W0i, const u16* __restrict__ W0h,
            const u16* __restrict__ W1i, const u16* __restrict__ W1h,
            const float* __restrict__ bs0, const float* __restrict__ bs1,
            const int* __restrict__ reset,   // (T,B)
            const float* __restrict__ c0,    // (2,B,H)
            u16* __restrict__ h0seq,         // [T][B][H] layer0 output sequence
            u16* __restrict__ bufA0,         // [2][B][H] layer0 h-self (L2-local)
            u16* __restrict__ bufA1,         // [2][B][H] layer1 h-self (L2-local)
            float* __restrict__ hidden,      // (T,B,H)
            float* __restrict__ hn,          // (2,B,H)
            float* __restrict__ cn,          // (2,B,H)
            int* __restrict__ arr) {         // 256 flag slots, one per WG
  extern __shared__ char smem_raw[];
  u16*   wlds = (u16*)smem_raw;                 // 128KB frag-blocked weights
  float* xch  = (float*)(smem_raw + W_BYTES);   // 32KB: 8 rt-tiles x 1024 f32

  const int tid   = threadIdx.x;
  const int wg    = blockIdx.x;
  const int lb    = wg & 7;
  const int layer = lb >> 2;
  const int bg    = lb & 3;
  const int cg    = wg >> 3;
  const int hbase = cg * 16;
  const int rowbase = bg * 128;
  const int wave  = tid >> 6;                  // 0..15
  const int lane  = tid & 63;
  const int r16   = lane & 15;
  const int kq    = lane >> 4;                 // 0..3
  const int rt    = wave & 7;                  // row-tile 0..7
  const int hf    = wave >> 3;                 // 0 = x-part, 1 = h-part
  const int wrow0 = rowbase + rt * 16;

  const u16* Wih = layer ? W1i : W0i;
  const u16* Whh = layer ? W1h : W0h;
  const float* bs = layer ? bs1 : bs0;
  u16* bufA_self = layer ? bufA1 : bufA0;

  // poll slots (wave 0 only): L0 -> own set; L1 -> pair set
  const int slotOwn  = (lane & 31) * 8 + bg;
  const int slotPair = (lane >> 1) * 8 + (lane & 1) * 4 + bg;

  // ---- stage weights into frag-blocked LDS (once) ----
  // chunk c = fb*64 + l ; fb = ni*32 + kslot ; kslot<16 -> W_ih, else W_hh
  for (int it = 0; it < 8; ++it) {
    int c = it * 1024 + tid;                   // 0..8191
    int fb = c >> 6, l = c & 63;
    int ni = fb >> 5, kslot = fb & 31;
    int col = hbase + (l & 15);
    int klocal = (kslot & 15) * 32 + (l >> 4) * 8;
    const u16* M = (kslot < 16) ? Wih : Whh;
    const u16* src = M + (size_t)(ni * H_ + col) * K_ + klocal;
    *(float4*)(wlds + ((size_t)c) * 8) = *(const float4*)src;
  }

  // per-lane gate biases (col = hbase + r16)
  float bias[4];
  #pragma unroll
  for (int g = 0; g < 4; ++g) bias[g] = bs[g * H_ + hbase + r16];

  // c-state registers (used by hf0 waves): j -> row = wrow0 + kq*4 + j
  float creg[4];
  #pragma unroll
  for (int j = 0; j < 4; ++j)
    creg[j] = c0[((size_t)layer * B_ + (wrow0 + kq * 4 + j)) * H_ + hbase + r16];

  __syncthreads();

  float* mytile = xch + (size_t)rt * 1024;     // this rt's exchange tile (4KB)

  for (int p = 0; p <= T_; ++p) {
    // L1-only invalidate: bufA lines written by sibling CUs last phase.
    if (p) { asm volatile("buffer_inv sc0" ::: "memory"); }

    const int t = layer ? (p - 1) : p;
    const bool active = (t >= 0 && t < T_);
    float hnew_r[4], cnew_r[4];

    f32x4 acc[4] = {};
    const int* rst_t = reset + (size_t)t * B_;

    if (active) {
      if (hf == 0) {
        // x-part: latent (L0) or h0seq[t] (L1, plain cached cold lines)
        const u16* X = layer ? (h0seq + (size_t)t * B_ * H_)
                             : (latb + (size_t)t * B_ * K_);
        const u16* x0 = X + (size_t)(wrow0 + r16) * K_ + kq * 8;
        #pragma unroll
        for (int s = 0; s < 16; ++s) {
          frag a = *reinterpret_cast<const frag*>(x0 + s * 32);
          #pragma unroll
          for (int ni = 0; ni < 4; ++ni) {
            frag b = *reinterpret_cast<const frag*>(
                wlds + ((size_t)((ni * 32 + s) * 64 + lane)) * 8);
            acc[ni] = __builtin_amdgcn_mfma_f32_16x16x32_bf16(a, b, acc[ni], 0, 0, 0);
          }
        }
      } else {
        // h-part: bufA parity, reset-masked rows
        const u16* Hp = bufA_self + (size_t)(p & 1) * B_ * H_;
        const u16* hp0 = Hp + (size_t)(wrow0 + r16) * H_ + kq * 8;
        const int ra0 = rst_t[wrow0 + r16];
        const frag zf = {};
        #pragma unroll
        for (int s = 0; s < 16; ++s) {
          frag a = ra0 ? zf : *reinterpret_cast<const frag*>(hp0 + s * 32);
          #pragma unroll
          for (int ni = 0; ni < 4; ++ni) {
            frag b = *reinterpret_cast<const frag*>(
                wlds + ((size_t)((ni * 32 + 16 + s) * 64 + lane)) * 8);
            acc[ni] = __builtin_amdgcn_mfma_f32_16x16x32_bf16(a, b, acc[ni], 0, 0, 0);
          }
        }
        // write partials: lane-consecutive f32x4 (conflict-free b128)
        #pragma unroll
        for (int ni = 0; ni < 4; ++ni)
          *(f32x4*)(mytile + ((size_t)ni * 64 + lane) * 4) = acc[ni];
      }
    }
    __syncthreads();   // partials visible to hf0 waves

    if (active && hf == 0) {
      u16* HnA  = bufA_self + (size_t)((p + 1) & 1) * B_ * H_;

      // add h-part partials
      #pragma unroll
      for (int ni = 0; ni < 4; ++ni)
        acc[ni] += *(const f32x4*)(mytile + ((size_t)ni * 64 + lane) * 4);

      // cell elementwise: lane-local (rows kq*4+j, col r16)
      float* hstg = mytile;                    // reuse own tile (in-wave order)
      #pragma unroll
      for (int j = 0; j < 4; ++j) {
        const int rstj = rst_t[wrow0 + kq * 4 + j];
        float gi = acc[0][j] + bias[0];
        float gf = acc[1][j] + bias[1];
        float gg = acc[2][j] + bias[2];
        float go = acc[3][j] + bias[3];
        float iv = 1.f / (1.f + __expf(-gi));
        float fv = 1.f / (1.f + __expf(-gf));
        float gv = 1.f - 2.f / (__expf(2.f * gg) + 1.f);   // tanh
        float ov = 1.f / (1.f + __expf(-go));
        float ce = rstj ? 0.f : creg[j];
        float cnew = fv * ce + iv * gv;
        float hnew = ov * (1.f - 2.f / (__expf(2.f * cnew) + 1.f));
        creg[j] = cnew;
        cnew_r[j] = cnew;
        hnew_r[j] = hnew;
        hstg[(kq * 4 + j) * 20 + r16] = hnew;  // [16][20] in own tile
      }

      // pack + h stores: lane -> (row = lane>>2, 4 cols at (lane&3)*4)
      {
        const int prow = lane >> 2;
        const int pc4  = lane & 3;
        float4 v = *reinterpret_cast<const float4*>(hstg + prow * 20 + pc4 * 4);
        bf16 b0 = __float2bfloat16(v.x), b1 = __float2bfloat16(v.y);
        bf16 b2 = __float2bfloat16(v.z), b3 = __float2bfloat16(v.w);
        u64 pk = (u64)*reinterpret_cast<u16*>(&b0)
               | ((u64)*reinterpret_cast<u16*>(&b1) << 16)
               | ((u64)*reinterpret_cast<u16*>(&b2) << 32)
               | ((u64)*reinterpret_cast<u16*>(&b3) << 48);
        const size_t hoff = (size_t)(wrow0 + prow) * H_ + hbase + pc4 * 4;
        *(u64*)(HnA + hoff) = pk;                       // plain -> local L2
        if (layer == 0) {
          __hip_atomic_store((u64*)(h0seq + (size_t)t * B_ * H_ + hoff), pk,
                             __ATOMIC_RELAXED, __HIP_MEMORY_SCOPE_AGENT);  // -> L3
        }
      }
    }

    // barrier arrival: own-slot flag store (no RMW), after h stores acked
    if (p < T_) {
      asm volatile("s_waitcnt vmcnt(0)" ::: "memory");
      __syncthreads();
      if (tid == 0)
        __hip_atomic_store(arr + wg, p + 1, __ATOMIC_RELAXED, __HIP_MEMORY_SCOPE_AGENT);
    }

    // deferred output stores (overlap with poll)
    if (active && hf == 0) {
      float* hidden_t = hidden + (size_t)t * B_ * H_;
      #pragma unroll
      for (int j = 0; j < 4; ++j) {
        const size_t off = (size_t)(wrow0 + kq * 4 + j) * H_ + hbase + r16;
        if (layer) hidden_t[off] = hnew_r[j];
        if (t == T_ - 1) {
          hn[(size_t)layer * B_ * H_ + off] = hnew_r[j];
          cn[(size_t)layer * B_ * H_ + off] = cnew_r[j];
        }
      }
    }

    // barrier wait — asymmetric (L0 own set, L1 pair set); wave 0 polls
    if (p < T_) {
      if (wave == 0) {
        if (layer == 0) {
          while (__hip_atomic_load(arr + slotOwn, __ATOMIC_RELAXED,
                                   __HIP_MEMORY_SCOPE_AGENT) < p + 1)
            __builtin_amdgcn_s_sleep(2);
        } else {
          while (__hip_atomic_load(arr + slotPair, __ATOMIC_RELAXED,
                                   __HIP_MEMORY_SCOPE_AGENT) < p + 1)
            __builtin_amdgcn_s_sleep(2);
        }
      }
      __syncthreads();
    }
  }
}

// ---------------- host ----------------

extern "C" void kernel_launch(void* const* d_in, const int* in_sizes, int n_in,
                              void* d_out, int out_size, void* d_ws, size_t ws_size,
                              hipStream_t stream) {
  (void)in_sizes; (void)n_in; (void)out_size; (void)ws_size;

  const float* latent = (const float*)d_in[0];
  const float* h0in   = (const float*)d_in[1];
  const float* c0in   = (const float*)d_in[2];
  const int*   reset  = (const int*)d_in[3];
  const float* W_ih0  = (const float*)d_in[4];
  const float* W_hh0  = (const float*)d_in[5];
  const float* b_ih0  = (const float*)d_in[6];
  const float* b_hh0  = (const float*)d_in[7];
  const float* W_ih1  = (const float*)d_in[8];
  const float* W_hh1  = (const float*)d_in[9];
  const float* b_ih1  = (const float*)d_in[10];
  const float* b_hh1  = (const float*)d_in[11];

  float* out    = (float*)d_out;
  float* hidden = out;                               // (T,B,H)
  float* hn     = out + (size_t)T_ * B_ * H_;        // (2,B,H)
  float* cn     = hn + (size_t)2 * B_ * H_;          // (2,B,H)

  // workspace layout (~138 MB)
  char* ws = (char*)d_ws;
  u16* latb  = (u16*)ws;                             // T*B*K bf16 (64 MiB)
  u16* wih0b = latb + (size_t)T_ * B_ * K_;
  u16* whh0b = wih0b + (size_t)G4_ * K_;
  u16* wih1b = whh0b + (size_t)G4_ * K_;
  u16* whh1b = wih1b + (size_t)G4_ * K_;
  float* bsum0 = (float*)(whh1b + (size_t)G4_ * K_);
  float* bsum1 = bsum0 + G4_;
  u16* h0seq = (u16*)(bsum1 + G4_);                  // [T][B][H] (64 MiB)
  u16* bufA0 = h0seq + (size_t)T_ * B_ * H_;         // [2][B][H] L2-local
  u16* bufA1 = bufA0 + (size_t)2 * B_ * H_;          // [2][B][H] L2-local
  int* arr   = (int*)(bufA1 + (size_t)2 * B_ * H_);  // 256 flag slots

  // conversions / init (stream-ordered)
  int n_lat4 = T_ * B_ * K_ / 4;
  k_f32_to_bf16_v4<<<2048, 256, 0, stream>>>((const float4*)latent, (ushort4*)latb, n_lat4);
  int n_w4 = G4_ * K_ / 4;
  k_f32_to_bf16_v4<<<256, 256, 0, stream>>>((const float4*)W_ih0, (ushort4*)wih0b, n_w4);
  k_f32_to_bf16_v4<<<256, 256, 0, stream>>>((const float4*)W_hh0, (ushort4*)whh0b, n_w4);
  k_f32_to_bf16_v4<<<256, 256, 0, stream>>>((const float4*)W_ih1, (ushort4*)wih1b, n_w4);
  k_f32_to_bf16_v4<<<256, 256, 0, stream>>>((const float4*)W_hh1, (ushort4*)whh1b, n_w4);
  k_bias<<<(G4_ + 255) / 256, 256, 0, stream>>>(b_ih0, b_hh0, b_ih1, b_hh1, bsum0, bsum1);
  k_init2<<<(B_ * H_ + 255) / 256, 256, 0, stream>>>(h0in, bufA0, bufA1);
  k_zero<<<1, 256, 0, stream>>>(arr);

  // persistent cooperative kernel
  hipFuncSetAttribute((const void*)k_main, hipFuncAttributeMaxDynamicSharedMemorySize,
                      (int)SMEM_BYTES);
  void* args[] = { (void*)&latb, (void*)&wih0b, (void*)&whh0b, (void*)&wih1b, (void*)&whh1b,
                   (void*)&bsum0, (void*)&bsum1, (void*)&reset, (void*)&c0in,
                   (void*)&h0seq, (void*)&bufA0, (void*)&bufA1,
                   (void*)&hidden, (void*)&hn, (void*)&cn, (void*)&arr };
  hipLaunchCooperativeKernel((void*)k_main, dim3(NWG), dim3(1024), args,
                             (unsigned int)SMEM_BYTES, stream);
}

// Round 19
// 1399.975 us; speedup vs baseline: 1.0167x; 1.0167x over previous
//
#include <hip/hip_runtime.h>
#include <hip/hip_bf16.h>

typedef __hip_bfloat16 bf16;
typedef unsigned short u16;
typedef unsigned long long u64;
using frag  = __attribute__((ext_vector_type(8))) short;   // 8 bf16
using f32x4 = __attribute__((ext_vector_type(4))) float;   // 4 fp32 acc

static constexpr int T_  = 128;
static constexpr int B_  = 512;
static constexpr int H_  = 512;
static constexpr int K_  = 512;
static constexpr int G4_ = 2048;
static constexpr int NWG = 256;

// dynamic LDS: frag-blocked weights only (128 blocks x 1KB)
static constexpr size_t W_BYTES = 131072;
static constexpr size_t SMEM_BYTES = W_BYTES;

// ---------------- setup kernels ----------------

__global__ void k_f32_to_bf16_v4(const float4* __restrict__ src,
                                 ushort4* __restrict__ dst, int n4) {
  int i = blockIdx.x * blockDim.x + threadIdx.x;
  int stride = gridDim.x * blockDim.x;
  for (; i < n4; i += stride) {
    float4 v = src[i];
    ushort4 o;
    bf16 t0 = __float2bfloat16(v.x); o.x = *reinterpret_cast<u16*>(&t0);
    bf16 t1 = __float2bfloat16(v.y); o.y = *reinterpret_cast<u16*>(&t1);
    bf16 t2 = __float2bfloat16(v.z); o.z = *reinterpret_cast<u16*>(&t2);
    bf16 t3 = __float2bfloat16(v.w); o.w = *reinterpret_cast<u16*>(&t3);
    dst[i] = o;
  }
}

__global__ void k_bias(const float* __restrict__ bih0, const float* __restrict__ bhh0,
                       const float* __restrict__ bih1, const float* __restrict__ bhh1,
                       float* __restrict__ bsum0, float* __restrict__ bsum1) {
  int i = blockIdx.x * blockDim.x + threadIdx.x;
  if (i < G4_) {
    bsum0[i] = bih0[i] + bhh0[i];
    bsum1[i] = bih1[i] + bhh1[i];
  }
}

// initial h into per-layer L2-local buffers: layer0 -> bufA0 par0, layer1 -> bufA1 par1
__global__ void k_init2(const float* __restrict__ h0,
                        u16* __restrict__ bufA0, u16* __restrict__ bufA1) {
  int i = blockIdx.x * blockDim.x + threadIdx.x;
  int n = B_ * H_;
  if (i < n) {
    bf16 a = __float2bfloat16(h0[i]);
    bf16 b = __float2bfloat16(h0[n + i]);
    bufA0[i] = *reinterpret_cast<u16*>(&a);          // parity 0
    bufA1[n + i] = *reinterpret_cast<u16*>(&b);      // parity 1
  }
}

__global__ void k_zero(int* p) {
  int i = blockIdx.x * blockDim.x + threadIdx.x;
  if (i < 256) p[i] = 0;
}

// ---------------- persistent LSTM kernel ----------------
// R17 base: 256 WGs x 512 thr, lb = wg&7 -> layer = lb>>2, bg = lb&3, cg = wg>>3;
// WG owns rows [bg*128,+128) x h-cols [cg*16,+16); wave w owns rows
// [bg*128 + w*16,+16), all 4 gates; frag-blocked weight LDS (conflict-free).
// h-self: bufA{layer}, plain L2 stores/loads + per-phase buffer_inv sc0 (L1-only).
// Cross-layer h0: t-indexed h0seq (L0 agent-atomic stores -> L3; L1 plain
// cached loads of cold lines -> shared L2 fill). Asymmetric flag barrier.
// NEW (R19): X-LOAD PIPELINING. At the tail of phase p (after arrival flag),
// issue phase p+1's 16 x-frag loads into registers (xfr[]), THEN poll.
// The poll-side __syncthreads drains vmcnt -> load latency hides under the
// poll (wait = max(poll, load), not poll + load). L1 pre-polls L0's flag set
// (normally already satisfied: L0 free-runs ahead) before issuing h0seq loads.
__global__ __launch_bounds__(512, 2)
void k_main(const u16* __restrict__ latb,
            const u16* __restrict__ W0i, const u16* __restrict__ W0h,
            const u16* __restrict__ W1i, const u16* __restrict__ W1h,
            const float* __restrict__ bs0, const float* __restrict__ bs1,
            const int* __restrict__ reset,   // (T,B)
            const float* __restrict__ c0,    // (2,B,H)
            u16* __restrict__ h0seq,         // [T][B][H] layer0 output sequence
            u16* __restrict__ bufA0,         // [2][B][H] layer0 h-self (L2-local)
            u16* __restrict__ bufA1,         // [2][B][H] layer1 h-self (L2-local)
            float* __restrict__ hidden,      // (T,B,H)
            float* __restrict__ hn,          // (2,B,H)
            float* __restrict__ cn,          // (2,B,H)
            int* __restrict__ arr) {         // 256 flag slots, one per WG
  extern __shared__ char smem_raw[];
  u16* wlds = (u16*)smem_raw;                // 128KB frag-blocked weights
  __shared__ float hstage[8][16][20];        // per-wave h packing tile

  const int tid   = threadIdx.x;
  const int wg    = blockIdx.x;
  const int lb    = wg & 7;
  const int layer = lb >> 2;
  const int bg    = lb & 3;
  const int cg    = wg >> 3;
  const int hbase = cg * 16;
  const int rowbase = bg * 128;
  const int wave  = tid >> 6;                  // 0..7
  const int lane  = tid & 63;
  const int r16   = lane & 15;
  const int kq    = lane >> 4;                 // 0..3
  const int wrow_local = wave * 16;            // wave's batch offset within WG
  const int wrow0 = rowbase + wrow_local;

  const u16* Wih = layer ? W1i : W0i;
  const u16* Whh = layer ? W1h : W0h;
  const float* bs = layer ? bs1 : bs0;
  u16* bufA_self = layer ? bufA1 : bufA0;

  // poll slots (wave 0 only)
  const int slotL0own = (lane & 31) * 8 + bg;        // L0 flag set of domain bg
  const int slotL1own = (lane & 31) * 8 + 4 + bg;    // L1 flag set of domain bg

  // ---- stage weights into frag-blocked LDS (once) ----
  // chunk c = fb*64 + l ; fb = ni*32 + kslot ; kslot<16 -> W_ih, else W_hh
  for (int it = 0; it < 16; ++it) {
    int c = it * 512 + tid;                    // 0..8191
    int fb = c >> 6, l = c & 63;
    int ni = fb >> 5, kslot = fb & 31;
    int col = hbase + (l & 15);
    int klocal = (kslot & 15) * 32 + (l >> 4) * 8;
    const u16* M = (kslot < 16) ? Wih : Whh;
    const u16* src = M + (size_t)(ni * H_ + col) * K_ + klocal;
    *(float4*)(wlds + ((size_t)c) * 8) = *(const float4*)src;
  }

  // per-lane gate biases (col = hbase + r16)
  float bias[4];
  #pragma unroll
  for (int g = 0; g < 4; ++g) bias[g] = bs[g * H_ + hbase + r16];

  // c-state registers: j -> row = wrow0 + kq*4 + j, col = hbase + r16
  float creg[4];
  #pragma unroll
  for (int j = 0; j < 4; ++j)
    creg[j] = c0[((size_t)layer * B_ + (wrow0 + kq * 4 + j)) * H_ + hbase + r16];

  // ---- prologue: hoist phase-0 x loads (L0 only; L1 inactive at p=0) ----
  frag xfr[16];
  if (layer == 0) {
    const u16* x0 = latb + (size_t)(wrow0 + r16) * K_ + kq * 8;   // t = 0
    #pragma unroll
    for (int s = 0; s < 16; ++s)
      xfr[s] = *reinterpret_cast<const frag*>(x0 + s * 32);
  }

  __syncthreads();

  for (int p = 0; p <= T_; ++p) {
    // L1-only invalidate: bufA lines written by sibling CUs last phase.
    // Register-held xfr is unaffected.
    if (p) { asm volatile("buffer_inv sc0" ::: "memory"); }

    const int t = layer ? (p - 1) : p;
    const bool active = (t >= 0 && t < T_);
    float hnew_r[4], cnew_r[4];

    if (active) {
      const u16* Hp = bufA_self + (size_t)(p & 1) * B_ * H_;
      u16* HnA      = bufA_self + (size_t)((p + 1) & 1) * B_ * H_;

      const int* rst_t = reset + (size_t)t * B_;
      const int ra0 = rst_t[wrow0 + r16];           // mask for this lane's A row
      const u16* hp0 = Hp + (size_t)(wrow0 + r16) * H_ + kq * 8;

      f32x4 acc[4] = {};
      const frag zf = {};

      // merged x+h K-loop: x from pre-loaded regs, h plain loads, frag-blocked B
      #pragma unroll
      for (int s = 0; s < 16; ++s) {
        frag ah = ra0 ? zf : *reinterpret_cast<const frag*>(hp0 + s * 32);
        #pragma unroll
        for (int ni = 0; ni < 4; ++ni) {
          frag bx = *reinterpret_cast<const frag*>(
              wlds + ((size_t)((ni * 32 + s) * 64 + lane)) * 8);
          frag bh = *reinterpret_cast<const frag*>(
              wlds + ((size_t)((ni * 32 + 16 + s) * 64 + lane)) * 8);
          acc[ni] = __builtin_amdgcn_mfma_f32_16x16x32_bf16(xfr[s], bx, acc[ni], 0, 0, 0);
          acc[ni] = __builtin_amdgcn_mfma_f32_16x16x32_bf16(ah,     bh, acc[ni], 0, 0, 0);
        }
      }

      // cell elementwise: lane-local (4 outputs: rows kq*4+j, col r16)
      #pragma unroll
      for (int j = 0; j < 4; ++j) {
        const int rstj = rst_t[wrow0 + kq * 4 + j];
        float gi = acc[0][j] + bias[0];
        float gf = acc[1][j] + bias[1];
        float gg = acc[2][j] + bias[2];
        float go = acc[3][j] + bias[3];
        float iv = 1.f / (1.f + __expf(-gi));
        float fv = 1.f / (1.f + __expf(-gf));
        float gv = 1.f - 2.f / (__expf(2.f * gg) + 1.f);   // tanh
        float ov = 1.f / (1.f + __expf(-go));
        float ce = rstj ? 0.f : creg[j];
        float cnew = fv * ce + iv * gv;
        float hnew = ov * (1.f - 2.f / (__expf(2.f * cnew) + 1.f));
        creg[j] = cnew;
        cnew_r[j] = cnew;
        hnew_r[j] = hnew;
        hstage[wave][kq * 4 + j][r16] = hnew;   // wave-local LDS (in-wave order)
      }

      // pack + h stores: lane -> (row = lane>>2, 4 cols at (lane&3)*4)
      {
        const int prow = lane >> 2;
        const int pc4  = lane & 3;
        float4 v = *reinterpret_cast<const float4*>(&hstage[wave][prow][pc4 * 4]);
        bf16 b0 = __float2bfloat16(v.x), b1 = __float2bfloat16(v.y);
        bf16 b2 = __float2bfloat16(v.z), b3 = __float2bfloat16(v.w);
        u64 pk = (u64)*reinterpret_cast<u16*>(&b0)
               | ((u64)*reinterpret_cast<u16*>(&b1) << 16)
               | ((u64)*reinterpret_cast<u16*>(&b2) << 32)
               | ((u64)*reinterpret_cast<u16*>(&b3) << 48);
        const size_t hoff = (size_t)(wrow0 + prow) * H_ + hbase + pc4 * 4;
        *(u64*)(HnA + hoff) = pk;                       // plain -> local L2
        if (layer == 0) {
          // timestep-indexed coherent store -> L3 (consumed by layer1 at p+1)
          __hip_atomic_store((u64*)(h0seq + (size_t)t * B_ * H_ + hoff), pk,
                             __ATOMIC_RELAXED, __HIP_MEMORY_SCOPE_AGENT);
        }
      }
    }

    // barrier arrival: own-slot flag store (no RMW), after h stores acked
    if (p < T_) {
      asm volatile("s_waitcnt vmcnt(0)" ::: "memory");
      __syncthreads();
      if (tid == 0)
        __hip_atomic_store(arr + wg, p + 1, __ATOMIC_RELAXED, __HIP_MEMORY_SCOPE_AGENT);
    }

    // deferred output stores (overlap with poll; nobody reads these in-kernel)
    if (active) {
      float* hidden_t = hidden + (size_t)t * B_ * H_;
      #pragma unroll
      for (int j = 0; j < 4; ++j) {
        const size_t off = (size_t)(wrow0 + kq * 4 + j) * H_ + hbase + r16;
        if (layer) hidden_t[off] = hnew_r[j];
        if (t == T_ - 1) {
          hn[(size_t)layer * B_ * H_ + off] = hnew_r[j];
          cn[(size_t)layer * B_ * H_ + off] = cnew_r[j];
        }
      }
    }

    // ---- tail: issue phase p+1 x loads, then poll (loads drain under poll) ----
    if (p < T_) {
      const int tn = layer ? p : (p + 1);      // next phase's timestep
      const bool nact = (tn < T_);

      if (layer == 1 && nact) {
        // L1 needs L0's phase-p flags before touching h0seq[t=p] (usually
        // already satisfied — L0 free-runs ahead under the asymmetric barrier)
        if (wave == 0) {
          while (__hip_atomic_load(arr + slotL0own, __ATOMIC_RELAXED,
                                   __HIP_MEMORY_SCOPE_AGENT) < p + 1)
            __builtin_amdgcn_s_sleep(2);
        }
        __syncthreads();
      }
      if (nact) {
        const u16* X = layer ? (h0seq + (size_t)tn * B_ * H_)
                             : (latb + (size_t)tn * B_ * K_);
        const u16* x0 = X + (size_t)(wrow0 + r16) * K_ + kq * 8;
        #pragma unroll
        for (int s = 0; s < 16; ++s)
          xfr[s] = *reinterpret_cast<const frag*>(x0 + s * 32);
      }

      // main poll: own layer's 32-slot set (asymmetric barrier semantics)
      if (wave == 0) {
        const int slot = layer ? slotL1own : slotL0own;
        while (__hip_atomic_load(arr + slot, __ATOMIC_RELAXED,
                                 __HIP_MEMORY_SCOPE_AGENT) < p + 1)
          __builtin_amdgcn_s_sleep(2);
      }
      __syncthreads();   // also drains the hoisted xfr loads (vmcnt 0)
    }
  }
}

// ---------------- host ----------------

extern "C" void kernel_launch(void* const* d_in, const int* in_sizes, int n_in,
                              void* d_out, int out_size, void* d_ws, size_t ws_size,
                              hipStream_t stream) {
  (void)in_sizes; (void)n_in; (void)out_size; (void)ws_size;

  const float* latent = (const float*)d_in[0];
  const float* h0in   = (const float*)d_in[1];
  const float* c0in   = (const float*)d_in[2];
  const int*   reset  = (const int*)d_in[3];
  const float* W_ih0  = (const float*)d_in[4];
  const float* W_hh0  = (const float*)d_in[5];
  const float* b_ih0  = (const float*)d_in[6];
  const float* b_hh0  = (const float*)d_in[7];
  const float* W_ih1  = (const float*)d_in[8];
  const float* W_hh1  = (const float*)d_in[9];
  const float* b_ih1  = (const float*)d_in[10];
  const float* b_hh1  = (const float*)d_in[11];

  float* out    = (float*)d_out;
  float* hidden = out;                               // (T,B,H)
  float* hn     = out + (size_t)T_ * B_ * H_;        // (2,B,H)
  float* cn     = hn + (size_t)2 * B_ * H_;          // (2,B,H)

  // workspace layout (~138 MB)
  char* ws = (char*)d_ws;
  u16* latb  = (u16*)ws;                             // T*B*K bf16 (64 MiB)
  u16* wih0b = latb + (size_t)T_ * B_ * K_;
  u16* whh0b = wih0b + (size_t)G4_ * K_;
  u16* wih1b = whh0b + (size_t)G4_ * K_;
  u16* whh1b = wih1b + (size_t)G4_ * K_;
  float* bsum0 = (float*)(whh1b + (size_t)G4_ * K_);
  float* bsum1 = bsum0 + G4_;
  u16* h0seq = (u16*)(bsum1 + G4_);                  // [T][B][H] (64 MiB)
  u16* bufA0 = h0seq + (size_t)T_ * B_ * H_;         // [2][B][H] L2-local
  u16* bufA1 = bufA0 + (size_t)2 * B_ * H_;          // [2][B][H] L2-local
  int* arr   = (int*)(bufA1 + (size_t)2 * B_ * H_);  // 256 flag slots

  // conversions / init (stream-ordered)
  int n_lat4 = T_ * B_ * K_ / 4;
  k_f32_to_bf16_v4<<<2048, 256, 0, stream>>>((const float4*)latent, (ushort4*)latb, n_lat4);
  int n_w4 = G4_ * K_ / 4;
  k_f32_to_bf16_v4<<<256, 256, 0, stream>>>((const float4*)W_ih0, (ushort4*)wih0b, n_w4);
  k_f32_to_bf16_v4<<<256, 256, 0, stream>>>((const float4*)W_hh0, (ushort4*)whh0b, n_w4);
  k_f32_to_bf16_v4<<<256, 256, 0, stream>>>((const float4*)W_ih1, (ushort4*)wih1b, n_w4);
  k_f32_to_bf16_v4<<<256, 256, 0, stream>>>((const float4*)W_hh1, (ushort4*)whh1b, n_w4);
  k_bias<<<(G4_ + 255) / 256, 256, 0, stream>>>(b_ih0, b_hh0, b_ih1, b_hh1, bsum0, bsum1);
  k_init2<<<(B_ * H_ + 255) / 256, 256, 0, stream>>>(h0in, bufA0, bufA1);
  k_zero<<<1, 256, 0, stream>>>(arr);

  // persistent cooperative kernel
  hipFuncSetAttribute((const void*)k_main, hipFuncAttributeMaxDynamicSharedMemorySize,
                      (int)SMEM_BYTES);
  void* args[] = { (void*)&latb, (void*)&wih0b, (void*)&whh0b, (void*)&wih1b, (void*)&whh1b,
                   (void*)&bsum0, (void*)&bsum1, (void*)&reset, (void*)&c0in,
                   (void*)&h0seq, (void*)&bufA0, (void*)&bufA1,
                   (void*)&hidden, (void*)&hn, (void*)&cn, (void*)&arr };
  hipLaunchCooperativeKernel((void*)k_main, dim3(NWG), dim3(512), args,
                             (unsigned int)SMEM_BYTES, stream);
}